// Round 8
// baseline (180.403 us; speedup 1.0000x reference)
//
#include <hip/hip_runtime.h>
#include <stdint.h>

// Problem constants (fixed by the reference):
#define B 16
#define C 64
#define N 65536   // 256*256 positions
#define K 64

#define NBINS 4096        // bits>>19 of a positive f32 (exp8 + mant4)
#define LCAP  64          // per-block candidate region (expected ~20 = mean+10sigma)
#define NBLK  128         // blocks per batch in kernel 1 (512 positions each)
#define RTOT  (NBLK * LCAP)   // 8192 flattened candidate slots per batch
#define SCAP  2048        // survivor capacity after binT filter (expected ~150-400)
#define T0_BITS 0x42AA0000u   // 85.0f pre-threshold; 64th-largest chi^2(64) of 65536 ~ 105

// ws layout (no zeroing needed anywhere -- every word read is written first):
//   cnt    : B*NBLK u32            = 8 KiB   (plain stores, one per block)
//   cand_v : B*RTOT u32            = 512 KiB (fixed per-block regions)
//   cand_i : B*RTOT u32            = 512 KiB
#define CNT_OFF 0
#define CV_OFF  ((size_t)B * NBLK * sizeof(uint32_t))
#define CI_OFF  (CV_OFF + (size_t)B * RTOT * sizeof(uint32_t))

// ---------------------------------------------------------------------------
// ATTRIBUTION PROBE ROUND: kernel 1 runs its identical full sweep `reps` (=4)
// times (runtime arg so the compiler keeps the loop and the loads). Each rep
// writes the same candidate data (idempotent -> deterministic output). This
// lifts k1's dispatch above the harness's ~155us poison-fills so rocprof's
// top-5 finally shows OUR counters. Single-sweep cost = dur/4.
// ---------------------------------------------------------------------------
__global__ __launch_bounds__(256) void powsum_collect_kernel(const float* __restrict__ x,
                                                             uint32_t* __restrict__ cnt,
                                                             uint32_t* __restrict__ cand_v,
                                                             uint32_t* __restrict__ cand_i,
                                                             int reps) {
    __shared__ uint32_t l_cnt;
    __shared__ uint32_t l_v[LCAP], l_i[LCAP];

    const int b   = blockIdx.x >> 7;     // 128 blocks per batch
    const int blk = blockIdx.x & 127;
    const int n2  = blk * 512 + threadIdx.x * 2;   // 256 threads * 2 = 512 pos/block

    const float2* xp = (const float2*)(x + (size_t)b * C * N + n2);
    const size_t rbase = ((size_t)b * NBLK + blk) * LCAP;

    for (int rep = 0; rep < reps; ++rep) {
        __syncthreads();                     // protect l_v/l_i from prior rep's readers
        if (threadIdx.x == 0) l_cnt = 0u;
        __syncthreads();

        float2 acc = {0.f, 0.f};
        #pragma unroll 8
        for (int c = 0; c < C; ++c) {
            float2 v = xp[(size_t)c * (N / 2)];
            acc.x += v.x * v.x;
            acc.y += v.y * v.y;
        }

        const uint32_t vv[2] = {__float_as_uint(acc.x), __float_as_uint(acc.y)};
        #pragma unroll
        for (int j = 0; j < 2; ++j) {
            if (vv[j] > T0_BITS) {              // rare: ~3-4% of positions
                uint32_t p = atomicAdd(&l_cnt, 1u);     // LDS atomic: block-local
                if (p < LCAP) { l_v[p] = vv[j]; l_i[p] = (uint32_t)(n2 + j); }
            }
        }
        __syncthreads();

        const uint32_t m = (l_cnt < (uint32_t)LCAP) ? l_cnt : (uint32_t)LCAP;
        if (threadIdx.x == 0) cnt[b * NBLK + blk] = m;      // plain store
        if (threadIdx.x < m) {                              // m <= 64: one wave
            cand_v[rbase + threadIdx.x] = l_v[threadIdx.x];
            cand_i[rbase + threadIdx.x] = l_i[threadIdx.x];
        }
    }
}

// ---------------------------------------------------------------------------
// Kernel 2: unchanged from round 7 (measured as the residual this round).
// 256 blocks x 256 threads = 16 blocks per batch; redundant exact selection,
// each block gathers its own 4 of the 64 output rows.
// ---------------------------------------------------------------------------
__global__ __launch_bounds__(256) void select_gather_kernel(const float* __restrict__ x,
                                                            const uint32_t* __restrict__ cnt,
                                                            const uint32_t* __restrict__ cand_v,
                                                            const uint32_t* __restrict__ cand_i,
                                                            float* __restrict__ out) {
    const int b   = blockIdx.x >> 4;    // 16 blocks per batch
    const int q   = blockIdx.x & 15;    // this block's quarter of the rows
    const int tid = threadIdx.x;

    __shared__ uint32_t lh[NBINS];          // 16 KiB
    __shared__ uint32_t rc[NBLK];           // per-region counts
    __shared__ uint32_t csum[256];
    __shared__ uint32_t sh_binT;
    __shared__ uint32_t sv[SCAP], si[SCAP]; // 16 KiB
    __shared__ uint32_t scnt;
    __shared__ uint32_t sel[K];

    const uint32_t* cvb = cand_v + (size_t)b * RTOT;
    const uint32_t* cib = cand_i + (size_t)b * RTOT;

    // ---- 1) counts + histogram of candidates ------------------------------
    for (int j = tid; j < NBINS; j += 256) lh[j] = 0u;
    if (tid < NBLK) rc[tid] = cnt[b * NBLK + tid];
    if (tid == 0) scnt = 0u;
    __syncthreads();

    for (uint32_t i = tid; i < RTOT; i += 256) {        // 32 iterations
        const uint32_t r = i >> 6, j = i & (LCAP - 1);  // region, slot
        if (j < rc[r]) atomicAdd(&lh[cvb[i] >> 19], 1u);
    }
    __syncthreads();

    // ---- 2) suffix-scan -> binT -------------------------------------------
    uint32_t h[16];
    #pragma unroll
    for (int j = 0; j < 16; ++j) h[j] = lh[tid * 16 + j];
    uint32_t s = 0;
    #pragma unroll
    for (int j = 0; j < 16; ++j) s += h[j];
    csum[tid] = s;
    __syncthreads();
    for (int off = 1; off < 256; off <<= 1) {   // inclusive suffix scan
        uint32_t v = csum[tid] + ((tid + off < 256) ? csum[tid + off] : 0u);
        __syncthreads();
        csum[tid] = v;
        __syncthreads();
    }
    uint32_t ls[17];
    ls[16] = (tid < 255) ? csum[tid + 1] : 0u;
    #pragma unroll
    for (int j = 15; j >= 0; --j) ls[j] = ls[j + 1] + h[j];
    #pragma unroll
    for (int j = 0; j < 16; ++j) {
        if (ls[j] >= K && ls[j + 1] < K) sh_binT = (uint32_t)(tid * 16 + j);
    }
    __syncthreads();
    const uint32_t binT = sh_binT;

    // ---- 3) filter survivors ----------------------------------------------
    for (uint32_t i = tid; i < RTOT; i += 256) {
        const uint32_t r = i >> 6, j = i & (LCAP - 1);
        if (j < rc[r]) {
            const uint32_t v = cvb[i];
            if ((v >> 19) >= binT) {
                uint32_t p = atomicAdd(&scnt, 1u);
                if (p < SCAP) { sv[p] = v; si[p] = cib[i]; }
            }
        }
    }
    __syncthreads();
    const uint32_t M = (scnt < (uint32_t)SCAP) ? scnt : (uint32_t)SCAP;

    // ---- 4) exact rank sort (value desc, idx asc) -------------------------
    for (uint32_t t = tid; t < M; t += 256) {
        const uint32_t v = sv[t], id = si[t];
        uint32_t r = 0;
        for (uint32_t j = 0; j < M; ++j) {       // LDS broadcast reads
            const uint32_t vj = sv[j], ij = si[j];
            r += (vj > v || (vj == v && ij < id)) ? 1u : 0u;
        }
        if (r < K) sel[r] = id;
    }
    __syncthreads();

    // ---- 5) gather this block's 4 rows: out[b][k][c] = x[b][c][n_k] -------
    const int c = tid & 63;
    const int k = q * 4 + (tid >> 6);
    const uint32_t n = sel[k];
    out[((size_t)b * K + k) * C + c] = x[((size_t)b * C + c) * N + n];
}

// ---------------------------------------------------------------------------
extern "C" void kernel_launch(void* const* d_in, const int* in_sizes, int n_in,
                              void* d_out, int out_size, void* d_ws, size_t ws_size,
                              hipStream_t stream) {
    const float* x   = (const float*)d_in[0];
    float*       out = (float*)d_out;
    char*        ws  = (char*)d_ws;

    uint32_t* cnt    = (uint32_t*)(ws + CNT_OFF);
    uint32_t* cand_v = (uint32_t*)(ws + CV_OFF);
    uint32_t* cand_i = (uint32_t*)(ws + CI_OFF);

    powsum_collect_kernel<<<dim3(B * NBLK), dim3(256), 0, stream>>>(x, cnt, cand_v, cand_i, 4);
    select_gather_kernel<<<dim3(B * 16), dim3(256), 0, stream>>>(x, cnt, cand_v, cand_i, out);
}

// Round 9
// 138.673 us; speedup vs baseline: 1.3009x; 1.3009x over previous
//
#include <hip/hip_runtime.h>
#include <stdint.h>

// Problem constants (fixed by the reference):
#define B 16
#define C 64
#define N 65536   // 256*256 positions
#define K 64

#define NBINS 4096        // bits>>19 of a positive f32 (exp8 + mant4)
#define LCAP  64          // per-block candidate region (expected ~15 = mean+12sigma)
#define NBLK  128         // blocks per batch (512 positions each)
#define RTOT  (NBLK * LCAP)   // 8192 candidate slots per batch
#define SCAP  1024        // survivor capacity after binT filter (expected ~70-200)
#define T0_BITS 0x42AA0000u   // 85.0f pre-threshold; 64th-largest chi^2(64) of 65536 ~ 105
#define MAGIC   0xBEEF0000u   // distinguishes a written count from 0xAA poison / zeros
#define DESIG   127           // designated selector block per batch

// ws layout (NO zeroing needed: flags carry MAGIC; data reads are flag-guarded):
//   cnt    : B*NBLK u32   = 8 KiB   (MAGIC|m flags, release-stored)
//   cand_v : B*RTOT u32   = 512 KiB (fixed per-block regions, agent-scope stores)
//   cand_i : B*RTOT u32   = 512 KiB
#define CNT_OFF 0
#define CV_OFF  ((size_t)B * NBLK * sizeof(uint32_t))
#define CI_OFF  (CV_OFF + (size_t)B * RTOT * sizeof(uint32_t))

__device__ inline uint32_t agent_load(const uint32_t* p) {
    return __hip_atomic_load(p, __ATOMIC_RELAXED, __HIP_MEMORY_SCOPE_AGENT);
}

// ---------------------------------------------------------------------------
// Single fused kernel: 2048 blocks x 256 threads.
// Phase 1 (all blocks): bit-identical powsum stream (float2, sequential c);
//   candidates staged in LDS, written to this block's private region with
//   agent-scope stores, then flag := MAGIC|m (release).
// Phase 2 (block blk==DESIG of each batch): acquire-spin on the batch's 128
//   flags, then exact selection (hist -> binT -> filter -> rank-sort) and the
//   full 64-row gather. Overlaps the tail of other batches' streams.
// Deterministic: data written is a pure function of x; stale reads from a
//   previous identical call are bit-identical, so any interleaving yields the
//   same output.
// ---------------------------------------------------------------------------
__global__ __launch_bounds__(256) void spab_fused_kernel(const float* __restrict__ x,
                                                         uint32_t* __restrict__ cnt,
                                                         uint32_t* __restrict__ cand_v,
                                                         uint32_t* __restrict__ cand_i,
                                                         float* __restrict__ out) {
    __shared__ uint32_t l_cnt;
    __shared__ uint32_t l_v[LCAP], l_i[LCAP];
    // selection state (used only by designated blocks; LDS ~26.5 KiB total)
    __shared__ uint32_t rc[NBLK];
    __shared__ uint32_t lh[NBINS];
    __shared__ uint32_t csum[256];
    __shared__ uint32_t sh_binT, scnt;
    __shared__ uint32_t sv[SCAP], si[SCAP];
    __shared__ uint32_t sel[K];

    const int b   = blockIdx.x >> 7;     // 128 blocks per batch
    const int blk = blockIdx.x & 127;
    const int tid = threadIdx.x;
    const int n2  = blk * 512 + tid * 2;

    if (tid == 0) l_cnt = 0u;
    __syncthreads();

    // ---- phase 1: powsum (bit-identical to rounds 5-8) --------------------
    const float2* xp = (const float2*)(x + (size_t)b * C * N + n2);
    float2 acc = {0.f, 0.f};
    #pragma unroll 8
    for (int c = 0; c < C; ++c) {
        float2 v = xp[(size_t)c * (N / 2)];
        acc.x += v.x * v.x;
        acc.y += v.y * v.y;
    }

    const uint32_t vv[2] = {__float_as_uint(acc.x), __float_as_uint(acc.y)};
    #pragma unroll
    for (int j = 0; j < 2; ++j) {
        if (vv[j] > T0_BITS) {                       // rare: ~3% of positions
            uint32_t p = atomicAdd(&l_cnt, 1u);      // block-local LDS atomic
            if (p < LCAP) { l_v[p] = vv[j]; l_i[p] = (uint32_t)(n2 + j); }
        }
    }
    __syncthreads();

    const uint32_t m = (l_cnt < (uint32_t)LCAP) ? l_cnt : (uint32_t)LCAP;
    const size_t rbase = ((size_t)b * NBLK + blk) * LCAP;
    if (tid < m) {   // m <= 64: one wave; agent-scope stores -> coherent point
        __hip_atomic_store(&cand_v[rbase + tid], l_v[tid], __ATOMIC_RELAXED, __HIP_MEMORY_SCOPE_AGENT);
        __hip_atomic_store(&cand_i[rbase + tid], l_i[tid], __ATOMIC_RELAXED, __HIP_MEMORY_SCOPE_AGENT);
    }
    __syncthreads();    // drains vmcnt: data stores complete before the flag
    if (tid == 0)
        __hip_atomic_store(&cnt[b * NBLK + blk], MAGIC | m, __ATOMIC_RELEASE, __HIP_MEMORY_SCOPE_AGENT);

    if (blk != DESIG) return;

    // ---- phase 2: designated block -- exact selection + gather ------------
    for (int j = tid; j < NBINS; j += 256) lh[j] = 0u;
    if (tid == 0) scnt = 0u;

    // acquire-spin on the batch's 128 region flags (bounded for hang safety)
    for (int r = tid; r < NBLK; r += 256) {
        uint32_t v; int tries = 0;
        do {
            v = __hip_atomic_load(&cnt[b * NBLK + r], __ATOMIC_ACQUIRE, __HIP_MEMORY_SCOPE_AGENT);
            if ((v & 0xFFFF0000u) == MAGIC) break;
            __builtin_amdgcn_s_sleep(1);
        } while (++tries < (1 << 22));
        rc[r] = v & 0xFFFFu;
    }
    __syncthreads();

    const uint32_t* cvb = cand_v + (size_t)b * RTOT;
    const uint32_t* cib = cand_i + (size_t)b * RTOT;

    // 1) histogram of candidates (~2000)
    for (uint32_t i = tid; i < RTOT; i += 256) {
        const uint32_t r = i >> 6, j = i & (LCAP - 1);
        if (j < rc[r]) atomicAdd(&lh[agent_load(cvb + i) >> 19], 1u);
    }
    __syncthreads();

    // 2) suffix-scan -> binT = largest bin with suffix >= K (exact)
    uint32_t h[16];
    #pragma unroll
    for (int j = 0; j < 16; ++j) h[j] = lh[tid * 16 + j];
    uint32_t s = 0;
    #pragma unroll
    for (int j = 0; j < 16; ++j) s += h[j];
    csum[tid] = s;
    __syncthreads();
    for (int off = 1; off < 256; off <<= 1) {   // inclusive suffix scan
        uint32_t v = csum[tid] + ((tid + off < 256) ? csum[tid + off] : 0u);
        __syncthreads();
        csum[tid] = v;
        __syncthreads();
    }
    uint32_t ls[17];
    ls[16] = (tid < 255) ? csum[tid + 1] : 0u;
    #pragma unroll
    for (int j = 15; j >= 0; --j) ls[j] = ls[j + 1] + h[j];
    #pragma unroll
    for (int j = 0; j < 16; ++j) {
        if (ls[j] >= K && ls[j + 1] < K) sh_binT = (uint32_t)(tid * 16 + j);
    }
    __syncthreads();
    const uint32_t binT = sh_binT;

    // 3) filter survivors (bin >= binT)
    for (uint32_t i = tid; i < RTOT; i += 256) {
        const uint32_t r = i >> 6, j = i & (LCAP - 1);
        if (j < rc[r]) {
            const uint32_t v = agent_load(cvb + i);
            if ((v >> 19) >= binT) {
                uint32_t p = atomicAdd(&scnt, 1u);
                if (p < SCAP) { sv[p] = v; si[p] = agent_load(cib + i); }
            }
        }
    }
    __syncthreads();
    const uint32_t M = (scnt < (uint32_t)SCAP) ? scnt : (uint32_t)SCAP;

    // 4) exact rank sort (value desc, idx asc) == lax.top_k order
    for (uint32_t t = tid; t < M; t += 256) {
        const uint32_t v = sv[t], id = si[t];
        uint32_t r = 0;
        for (uint32_t j = 0; j < M; ++j) {       // LDS broadcast reads
            const uint32_t vj = sv[j], ij = si[j];
            r += (vj > v || (vj == v && ij < id)) ? 1u : 0u;
        }
        if (r < K) sel[r] = id;
    }
    __syncthreads();

    // 5) gather all 64 rows: out[b][k][c] = x[b][c][n_k]; 16 loads in flight
    const int c  = tid & 63;
    const int k0 = tid >> 6;
    const float* xb = x + ((size_t)b * C + c) * N;
    float vals[16];
    #pragma unroll
    for (int t = 0; t < 16; ++t) vals[t] = xb[sel[k0 + t * 4]];
    #pragma unroll
    for (int t = 0; t < 16; ++t) out[((size_t)b * K + (k0 + t * 4)) * C + c] = vals[t];
}

// ---------------------------------------------------------------------------
extern "C" void kernel_launch(void* const* d_in, const int* in_sizes, int n_in,
                              void* d_out, int out_size, void* d_ws, size_t ws_size,
                              hipStream_t stream) {
    const float* x   = (const float*)d_in[0];
    float*       out = (float*)d_out;
    char*        ws  = (char*)d_ws;

    uint32_t* cnt    = (uint32_t*)(ws + CNT_OFF);
    uint32_t* cand_v = (uint32_t*)(ws + CV_OFF);
    uint32_t* cand_i = (uint32_t*)(ws + CI_OFF);

    spab_fused_kernel<<<dim3(B * NBLK), dim3(256), 0, stream>>>(x, cnt, cand_v, cand_i, out);
}